// Round 16
// baseline (174.850 us; speedup 1.0000x reference)
//
#include <hip/hip_runtime.h>
#include <hip/hip_bf16.h>

// ---------------------------------------------------------------------------
// KEPCE_GCN, round 16 = R15 with k_edge at UE=8 (contiguous 2x uint4 stores).
//  R15 post-mortem: VGPR=20 is consistent with pipelined gathers (addr regs
//  consumed at issue) -- k_edge is near the L2 random-request-rate limit.
//  UE=8 halves per-edge index/stream/store instruction overhead and doubles
//  in-flight gathers; stores stay lane-contiguous (2x16B), unlike R12's
//  strided-4B mistake.
// ---------------------------------------------------------------------------

#define NNODES 100000
#define NREG   17
#define KB     782          // buckets = ceil(100000/128)
#define FBC    256          // chunk blocks
#define STCAP  12544        // LDS staging capacity (>= chunk)
#define LSTR64 19           // u64 row stride for AB planes (17 + pad)
#define ABSTR  4352         // 34*128 floats per bucket in ABg
#define QSCALE 4194304.0f   // 2^22
#define INVQ   2.384185791015625e-7f

// wsm element offsets (f32)
#define O_W0    0
#define O_B0    8
#define O_W1    16
#define O_B1    144
#define O_W2    160
#define O_B2C   672
#define O_WN    704
#define O_BN    1728
#define O_WE1   1760
#define O_BE1   3872
#define O_WE2   3904
#define O_BE2   3968
#define WSM_N   3970
#define O_H0    3972
#define O_TS    3992
#define O_NT    4008
#define O_U     4016   // 17*32
#define O_WWR   4560   // 17*32
#define O_M     5104   // 66*2
#define O_BIAS2 5236
#define WSM_TOTAL 6144

__device__ __forceinline__ float bf2f(unsigned short u) {
  union { float f; unsigned int i; } v; v.i = ((unsigned int)u) << 16; return v.f;
}
__device__ __forceinline__ unsigned short f2bf(float f) {
  union { float f; unsigned int i; } v; v.f = f;
  unsigned int x = v.i;
  return (unsigned short)((x + 0x7FFFu + ((x >> 16) & 1u)) >> 16);
}
__device__ __forceinline__ float relu_(float x) { return x > 0.f ? x : 0.f; }

// fused: dtype detect + weight convert + derived-tensor prep (one block)
__global__ __launch_bounds__(1024) void k_setup(
    const unsigned short* ewraw,
    const void* p0, const void* p1, const void* p2, const void* p3,
    const void* p4, const void* p5, const void* p6, const void* p7,
    const void* p8, const void* p9, const void* p10, const void* p11,
    int* mode, float* wsm) {
  __shared__ int cnt, smode, snt;
  __shared__ float h0[16], ts[16];
  int t = threadIdx.x;
  if (t == 0) cnt = 0;
  __syncthreads();
  int ok = 0;
  for (int i = t; i < 512; i += blockDim.x) {
    unsigned short h = ewraw[i];
    int e = (h >> 7) & 0xFF;
    if (!(h & 0x8000) && e >= 0x70 && e <= 0x7E) ok++;
  }
  atomicAdd(&cnt, ok);
  __syncthreads();
  if (t == 0) { smode = (cnt >= 400) ? 1 : 0; *mode = smode; }
  __syncthreads();
  int bf = smode;
  const void* ptrs[12] = {p0,p1,p2,p3,p4,p5,p6,p7,p8,p9,p10,p11};
  const int offs[13] = {O_W0,O_B0,O_W1,O_B1,O_W2,O_B2C,O_WN,O_BN,O_WE1,O_BE1,O_WE2,O_BE2,WSM_N};
  for (int idx = t; idx < WSM_N; idx += blockDim.x) {
    int seg = 0;
    while (idx >= offs[seg + 1]) seg++;
    int k = idx - offs[seg];
    wsm[idx] = bf ? bf2f(((const unsigned short*)ptrs[seg])[k])
                  : ((const float*)ptrs[seg])[k];
  }
  __syncthreads();
  if (t < 16) {
    float acc = 0.f;
    for (int j = 0; j < 8; j++)
      acc += (wsm[O_W0 + j] + wsm[O_B0 + j]) * wsm[O_W1 + j * 16 + t];
    h0[t] = acc;
    wsm[O_H0 + t] = acc;
  }
  __syncthreads();
  if (t == 0) {
    int n = 0;
    for (int j = 0; j < 16; j++) {
      float h = h0[j], b = wsm[O_B1 + j];
      if (h != 0.f) {
        float tj = -b / h;
        if (tj > 0.f) {
          int p = n++;
          while (p > 0 && ts[p - 1] > tj) { ts[p] = ts[p - 1]; p--; }
          ts[p] = tj;
        }
      }
    }
    snt = n;
    wsm[O_NT] = (float)n;
    for (int i = 0; i < n; i++) wsm[O_TS + i] = ts[i];
  }
  __syncthreads();
  int n = snt;
  for (int r = 0; r <= n; r++) {
    float srep;
    if (n == 0) srep = 1.f;
    else if (r == 0) srep = ts[0] * 0.5f;
    else if (r == n) srep = ts[n - 1] * 2.f + 1.f;
    else srep = 0.5f * (ts[r - 1] + ts[r]);
    if (t < 32) {
      float uu = 0.f, ww = 0.f;
      for (int j = 0; j < 16; j++) {
        float h = h0[j], b = wsm[O_B1 + j];
        if (srep * h + b > 0.f) {
          float w2 = wsm[O_W2 + j * 32 + t];
          uu += h * w2;
          ww += b * w2;
        }
      }
      wsm[O_U + r * 32 + t] = uu;
      wsm[O_WWR + r * 32 + t] = ww;
    }
  }
  for (int i = t; i < 66; i += blockDim.x) {
    float m0 = 0.f, m1 = 0.f;
    for (int k = 0; k < 32; k++) {
      float w1 = wsm[O_WE1 + i * 32 + k];
      m0 += w1 * wsm[O_WE2 + k * 2 + 0];
      m1 += w1 * wsm[O_WE2 + k * 2 + 1];
    }
    wsm[O_M + i * 2 + 0] = m0;
    wsm[O_M + i * 2 + 1] = m1;
  }
  if (t == 0) {
    float b20 = wsm[O_BE2 + 0], b21 = wsm[O_BE2 + 1];
    for (int k = 0; k < 32; k++) {
      b20 += wsm[O_BE1 + k] * wsm[O_WE2 + k * 2 + 0];
      b21 += wsm[O_BE1 + k] * wsm[O_WE2 + k * 2 + 1];
    }
    wsm[O_BIAS2 + 0] = b20;
    wsm[O_BIAS2 + 1] = b21;
  }
}

// --- bucket radix partition (atomic-free globally) -------------------------
__global__ __launch_bounds__(1024) void k_hist(const int* __restrict__ dst,
                                               int* __restrict__ counts,
                                               int E, int chunk) {
  __shared__ int h[KB];
  for (int i = threadIdx.x; i < KB; i += blockDim.x) h[i] = 0;
  __syncthreads();
  int b = blockIdx.x;
  int start = b * chunk, end = min(E, start + chunk);
  int tid = threadIdx.x, BD = blockDim.x;
  bool va = ((chunk & 3) == 0) && ((((unsigned long long)(const void*)dst) & 15ull) == 0ull);
  if (va) {
    for (int base = start; base < end; base += BD * 4) {
      int idx = base + tid * 4;
      if (idx + 4 <= end) {
        int4 d4 = *(const int4*)(dst + idx);
        atomicAdd(&h[d4.x >> 7], 1);
        atomicAdd(&h[d4.y >> 7], 1);
        atomicAdd(&h[d4.z >> 7], 1);
        atomicAdd(&h[d4.w >> 7], 1);
      } else {
        for (int e = idx; e < end; e++) atomicAdd(&h[dst[e] >> 7], 1);
      }
    }
  } else {
    for (int base = start; base < end; base += BD * 4) {
#pragma unroll
      for (int u = 0; u < 4; u++) {
        int idx = base + u * BD + tid;
        if (idx < end) atomicAdd(&h[dst[idx] >> 7], 1);
      }
    }
  }
  __syncthreads();
  for (int i = threadIdx.x; i < KB; i += blockDim.x)
    counts[i * FBC + b] = h[i];
}

__global__ __launch_bounds__(FBC) void k_scanA(const int* __restrict__ counts,
                                               int* __restrict__ prefx,
                                               int* __restrict__ totals) {
  __shared__ int s[FBC];
  int k = blockIdx.x, t = threadIdx.x;
  int v = counts[k * FBC + t];
  s[t] = v;
  __syncthreads();
  for (int off = 1; off < FBC; off <<= 1) {
    int add = (t >= off) ? s[t - off] : 0;
    __syncthreads();
    s[t] += add;
    __syncthreads();
  }
  prefx[k * FBC + t] = s[t] - v;
  if (t == FBC - 1) totals[k] = s[t];
}

__global__ __launch_bounds__(1024) void k_scanB(const int* __restrict__ totals,
                                                int* __restrict__ bases) {
  __shared__ int s[1024];
  int t = threadIdx.x;
  int v = (t < KB) ? totals[t] : 0;
  s[t] = v;
  __syncthreads();
  for (int off = 1; off < 1024; off <<= 1) {
    int add = (t >= off) ? s[t - off] : 0;
    __syncthreads();
    s[t] += add;
    __syncthreads();
  }
  if (t < KB) bases[t] = s[t] - v;
  if (t == KB - 1) bases[KB] = s[t];
}

__global__ __launch_bounds__(1024) void k_fillsort(const int* __restrict__ src,
                                                   const int* __restrict__ dst,
                                                   const int* __restrict__ counts,
                                                   const int* __restrict__ prefx,
                                                   const int* __restrict__ bases,
                                                   unsigned int* __restrict__ recs,
                                                   int E, int chunk) {
  __shared__ unsigned int staged[STCAP];
  __shared__ int cnt[KB], r0o[KB + 1], r0c[KB], tgt[KB];
  int b = blockIdx.x;
  int tid = threadIdx.x, BD = blockDim.x;
  for (int i = tid; i < KB; i += BD) {
    cnt[i] = counts[i * FBC + b];
    tgt[i] = bases[i] + prefx[i * FBC + b];
  }
  __syncthreads();
  int start = b * chunk, end = min(E, start + chunk);
  int rn = end - start;
  if (tid < KB) r0o[tid] = cnt[tid];
  __syncthreads();
  for (int off = 1; off < KB; off <<= 1) {
    int add = 0;
    if (tid < KB && tid >= off) add = r0o[tid - off];
    __syncthreads();
    if (tid < KB) r0o[tid] += add;
    __syncthreads();
  }
  if (tid < KB) r0c[tid] = r0o[tid] - cnt[tid];
  __syncthreads();
  if (tid < KB) r0o[tid] = r0c[tid];
  if (tid == 0) r0o[KB] = rn;
  __syncthreads();
  bool va = ((chunk & 3) == 0) &&
            ((((unsigned long long)(const void*)dst) & 15ull) == 0ull) &&
            ((((unsigned long long)(const void*)src) & 15ull) == 0ull);
  if (va) {
    for (int base = 0; base < rn; base += BD * 4) {
      int idx = base + tid * 4;
      if (idx + 4 <= rn) {
        int4 d4 = *(const int4*)(dst + start + idx);
        int4 s4 = *(const int4*)(src + start + idx);
        int p0 = atomicAdd(&r0c[d4.x >> 7], 1);
        staged[p0] = ((unsigned int)s4.x << 7) | (unsigned int)(d4.x & 127);
        int p1 = atomicAdd(&r0c[d4.y >> 7], 1);
        staged[p1] = ((unsigned int)s4.y << 7) | (unsigned int)(d4.y & 127);
        int p2 = atomicAdd(&r0c[d4.z >> 7], 1);
        staged[p2] = ((unsigned int)s4.z << 7) | (unsigned int)(d4.z & 127);
        int p3 = atomicAdd(&r0c[d4.w >> 7], 1);
        staged[p3] = ((unsigned int)s4.w << 7) | (unsigned int)(d4.w & 127);
      } else {
        for (int e2 = idx; e2 < rn; e2++) {
          int d = dst[start + e2];
          int s = src[start + e2];
          int pos = atomicAdd(&r0c[d >> 7], 1);
          staged[pos] = ((unsigned int)s << 7) | (unsigned int)(d & 127);
        }
      }
    }
  } else {
    for (int base = 0; base < rn; base += BD * 4) {
#pragma unroll
      for (int u = 0; u < 4; u++) {
        int idx = base + u * BD + tid;
        if (idx < rn) {
          int d = dst[start + idx];
          int s = src[start + idx];
          int pos = atomicAdd(&r0c[d >> 7], 1);
          staged[pos] = ((unsigned int)s << 7) | (unsigned int)(d & 127);
        }
      }
    }
  }
  __syncthreads();
  int nquads = (rn + 3) >> 2;
  for (int q = tid; q < nquads; q += BD) {
    int t0 = q * 4;
    int lo = 0, hi = KB;
    while (hi - lo > 1) {
      int mid = (lo + hi) >> 1;
      if (r0o[mid] <= t0) lo = mid; else hi = mid;
    }
    int tend = min(t0 + 4, rn);
    for (int t = t0; t < tend; t++) {
      while (t >= r0o[lo + 1]) lo++;
      recs[tgt[lo] + (t - r0o[lo])] = staged[t];
    }
  }
}

// --- per-bucket passes -----------------------------------------------------
#define UDG 4
__global__ __launch_bounds__(1024) void k_degdinv(const unsigned int* __restrict__ recs,
                                                  const int* __restrict__ bases,
                                                  float* __restrict__ dinv, int N) {
  __shared__ int cnt[128];
  if (threadIdx.x < 128) cnt[threadIdx.x] = 0;
  __syncthreads();
  int k = blockIdx.x;
  int s0 = bases[k], n = bases[k + 1] - s0;
  const unsigned int* rp = recs + s0;
  int tid = threadIdx.x, BD = blockDim.x;
  for (int base = 0; base < n; base += BD * UDG) {
    unsigned int r[UDG]; int ok[UDG];
#pragma unroll
    for (int u = 0; u < UDG; u++) {
      int idx = base + u * BD + tid;
      ok[u] = idx < n;
      r[u] = ok[u] ? rp[idx] : 0u;
    }
#pragma unroll
    for (int u = 0; u < UDG; u++)
      if (ok[u]) atomicAdd(&cnt[r[u] & 127u], 1);
  }
  __syncthreads();
  if (threadIdx.x < 128) {
    int v = k * 128 + threadIdx.x;
    if (v < N) dinv[v] = rsqrtf((float)cnt[threadIdx.x] + 1.0f);
  }
}

// emits recq = (alphaQ, betaQ, region, dv-bits)
#define USA 4
__global__ __launch_bounds__(1024) void k_sA(const float* __restrict__ wsm,
                                             const unsigned int* __restrict__ recs,
                                             const int* __restrict__ bases,
                                             const float* __restrict__ dinv,
                                             uint4* __restrict__ recq, int N) {
  __shared__ float acc[128];
  __shared__ float ts[16];
  __shared__ int nt;
  if (threadIdx.x < 128) acc[threadIdx.x] = 0.f;
  if (threadIdx.x == 0) nt = (int)wsm[O_NT];
  if (threadIdx.x < 16) ts[threadIdx.x] = wsm[O_TS + threadIdx.x];
  __syncthreads();
  int k = blockIdx.x;
  int s0 = bases[k], n = bases[k + 1] - s0;
  const unsigned int* rp = recs + s0;
  int tid = threadIdx.x, BD = blockDim.x;
  for (int base = 0; base < n; base += BD * USA) {
    unsigned int r[USA]; int ok[USA];
#pragma unroll
    for (int u = 0; u < USA; u++) {
      int idx = base + u * BD + tid;
      ok[u] = idx < n;
      r[u] = ok[u] ? rp[idx] : 0u;
    }
    float dv[USA];
#pragma unroll
    for (int u = 0; u < USA; u++) dv[u] = ok[u] ? dinv[r[u] >> 7] : 0.f;
#pragma unroll
    for (int u = 0; u < USA; u++)
      if (ok[u]) atomicAdd(&acc[r[u] & 127u], dv[u]);
  }
  __syncthreads();
  if (threadIdx.x < 128) {
    int v = k * 128 + threadIdx.x;
    if (v < N) {
      float dv = dinv[v];
      float s = dv * (acc[threadIdx.x] + dv);
      int rr = 0;
      for (int i = 0; i < nt; i++) rr += (ts[i] < s) ? 1 : 0;
      float alpha = dv * s;
      uint4 q;
      q.x = (unsigned int)(alpha * QSCALE + 0.5f);
      q.y = (unsigned int)(dv * QSCALE + 0.5f);
      q.z = (unsigned int)rr;
      q.w = __float_as_uint(dv);
      recq[v] = q;
    }
  }
}

// one packed u64 LDS atomic per edge; decode to ABg planes
#define UAB 4
__global__ __launch_bounds__(1024) void k_ABacc(const unsigned int* __restrict__ recs,
                                                const int* __restrict__ bases,
                                                const uint4* __restrict__ recq,
                                                float* __restrict__ ABg, int N) {
  __shared__ unsigned long long Lu[128 * LSTR64];
  for (int i = threadIdx.x; i < 128 * LSTR64; i += blockDim.x) Lu[i] = 0ull;
  __syncthreads();
  int k = blockIdx.x;
  int s0 = bases[k], n = bases[k + 1] - s0;
  const unsigned int* rp = recs + s0;
  int tid = threadIdx.x, BD = blockDim.x;
  for (int base = 0; base < n; base += BD * UAB) {
    unsigned int r[UAB]; int ok[UAB];
#pragma unroll
    for (int u = 0; u < UAB; u++) {
      int idx = base + u * BD + tid;
      ok[u] = idx < n;
      r[u] = ok[u] ? rp[idx] : 0u;
    }
    uint4 q[UAB];
#pragma unroll
    for (int u = 0; u < UAB; u++) {
      q[u] = make_uint4(0u, 0u, 0u, 0u);
      if (ok[u]) q[u] = recq[r[u] >> 7];
    }
#pragma unroll
    for (int u = 0; u < UAB; u++) {
      if (ok[u]) {
        unsigned long long c = ((unsigned long long)q[u].x << 32) | (unsigned long long)q[u].y;
        atomicAdd(&Lu[(int)(r[u] & 127u) * LSTR64 + (int)q[u].z], c);
      }
    }
  }
  __syncthreads();
  float* out = ABg + (size_t)k * ABSTR;
  for (int i = tid; i < 34 * 128; i += BD) {
    int r = i >> 7, v = i & 127;
    unsigned long long w;
    float val;
    if (r < NREG) {
      w = Lu[v * LSTR64 + r];
      val = (float)((unsigned int)(w >> 32)) * INVQ;
    } else {
      w = Lu[v * LSTR64 + (r - NREG)];
      val = (float)((unsigned int)(w & 0xFFFFFFFFull)) * INVQ;
    }
    out[i] = val;
  }
}

// per node: AB planes -> x2 -> x3 -> (ps, pd) split tables
__global__ __launch_bounds__(256) void k_node2(const float* __restrict__ wsm,
                                               const float* __restrict__ ABg,
                                               const uint4* __restrict__ recq,
                                               float2* __restrict__ ps2,
                                               float2* __restrict__ pd2, int N) {
  __shared__ float sU[NREG * 32], sW[NREG * 32], sB2[32], sWn[1024], sBn[32], sM[132];
  for (int i = threadIdx.x; i < NREG * 32; i += blockDim.x) {
    sU[i] = wsm[O_U + i];
    sW[i] = wsm[O_WWR + i];
  }
  for (int i = threadIdx.x; i < 1024; i += blockDim.x) sWn[i] = wsm[O_WN + i];
  if (threadIdx.x < 32) {
    sB2[threadIdx.x] = wsm[O_B2C + threadIdx.x];
    sBn[threadIdx.x] = wsm[O_BN + threadIdx.x];
  }
  for (int i = threadIdx.x; i < 132; i += blockDim.x) sM[i] = wsm[O_M + i];
  __syncthreads();
  int v = blockIdx.x * blockDim.x + threadIdx.x;
  if (v >= N) return;
  uint4 self = recq[v];
  float dv = __uint_as_float(self.w);
  float selfa = (float)self.x * INVQ;
  int sr = (int)self.z;
  const float* pb = ABg + (size_t)(v >> 7) * ABSTR + (v & 127);
  float A[NREG], B[NREG];
#pragma unroll
  for (int r = 0; r < NREG; r++) {
    A[r] = pb[r * 128];
    B[r] = pb[(NREG + r) * 128];
  }
  float acc[32];
#pragma unroll
  for (int j = 0; j < 32; j++) acc[j] = 0.f;
#pragma unroll
  for (int r = 0; r < NREG; r++) {
    float Ar = A[r] + ((r == sr) ? selfa : 0.f);
    float Br = B[r] + ((r == sr) ? dv : 0.f);
    if (Ar != 0.f || Br != 0.f) {
#pragma unroll
      for (int j = 0; j < 32; j++)
        acc[j] += Ar * sU[r * 32 + j] + Br * sW[r * 32 + j];
    }
  }
#pragma unroll
  for (int j = 0; j < 32; j++) acc[j] = relu_(dv * acc[j] + sB2[j]);  // x2
  float x3[32];
#pragma unroll
  for (int j = 0; j < 32; j++) {
    float a = sBn[j];
#pragma unroll
    for (int q2 = 0; q2 < 32; q2++) a += acc[q2] * sWn[q2 * 32 + j];
    x3[j] = relu_(a);
  }
  float ps0 = 0.f, ps1 = 0.f, pd0 = 0.f, pd1 = 0.f;
#pragma unroll
  for (int j = 0; j < 32; j++) {
    float x = x3[j];
    ps0 += x * sM[(2 + j) * 2 + 0];
    ps1 += x * sM[(2 + j) * 2 + 1];
    pd0 += x * sM[(34 + j) * 2 + 0];
    pd1 += x * sM[(34 + j) * 2 + 1];
  }
  ps2[v] = make_float2(ps0, ps1);
  pd2[v] = make_float2(pd0, pd1);
}

#define UE 8
__global__ __launch_bounds__(256, 4) void k_edge(const float* __restrict__ wsm,
                                                 const int* __restrict__ src,
                                                 const int* __restrict__ dst,
                                                 const void* __restrict__ ewraw,
                                                 const void* __restrict__ ceraw,
                                                 const float2* __restrict__ ps2,
                                                 const float2* __restrict__ pd2,
                                                 void* __restrict__ out,
                                                 const int* __restrict__ mode, int E) {
  int e0 = (blockIdx.x * blockDim.x + threadIdx.x) * UE;
  bool bf = (*mode) != 0;
  float b0 = wsm[O_BIAS2 + 0], b1 = wsm[O_BIAS2 + 1];
  float M00 = wsm[O_M + 0], M01 = wsm[O_M + 1];
  float M10 = wsm[O_M + 2], M11 = wsm[O_M + 3];
  if (e0 + UE <= E) {
    int4 sa = *(const int4*)(src + e0);
    int4 sb = *(const int4*)(src + e0 + 4);
    int4 da = *(const int4*)(dst + e0);
    int4 db = *(const int4*)(dst + e0 + 4);
    // 16 named gathers, all independent (SROA-friendly)
    float2 sv0 = ps2[sa.x];
    float2 sv1 = ps2[sa.y];
    float2 sv2 = ps2[sa.z];
    float2 sv3 = ps2[sa.w];
    float2 sv4 = ps2[sb.x];
    float2 sv5 = ps2[sb.y];
    float2 sv6 = ps2[sb.z];
    float2 sv7 = ps2[sb.w];
    float2 dv0 = pd2[da.x];
    float2 dv1 = pd2[da.y];
    float2 dv2 = pd2[da.z];
    float2 dv3 = pd2[da.w];
    float2 dv4 = pd2[db.x];
    float2 dv5 = pd2[db.y];
    float2 dv6 = pd2[db.z];
    float2 dv7 = pd2[db.w];
    float ew0, ew1, ew2, ew3, ew4, ew5, ew6, ew7;
    float ce0, ce1, ce2, ce3, ce4, ce5, ce6, ce7;
    if (bf) {
      uint4 ewp = *(const uint4*)((const unsigned short*)ewraw + e0);
      uint4 cep = *(const uint4*)((const unsigned short*)ceraw + e0);
      ew0 = bf2f((unsigned short)(ewp.x & 0xFFFFu));
      ew1 = bf2f((unsigned short)(ewp.x >> 16));
      ew2 = bf2f((unsigned short)(ewp.y & 0xFFFFu));
      ew3 = bf2f((unsigned short)(ewp.y >> 16));
      ew4 = bf2f((unsigned short)(ewp.z & 0xFFFFu));
      ew5 = bf2f((unsigned short)(ewp.z >> 16));
      ew6 = bf2f((unsigned short)(ewp.w & 0xFFFFu));
      ew7 = bf2f((unsigned short)(ewp.w >> 16));
      ce0 = bf2f((unsigned short)(cep.x & 0xFFFFu));
      ce1 = bf2f((unsigned short)(cep.x >> 16));
      ce2 = bf2f((unsigned short)(cep.y & 0xFFFFu));
      ce3 = bf2f((unsigned short)(cep.y >> 16));
      ce4 = bf2f((unsigned short)(cep.z & 0xFFFFu));
      ce5 = bf2f((unsigned short)(cep.z >> 16));
      ce6 = bf2f((unsigned short)(cep.w & 0xFFFFu));
      ce7 = bf2f((unsigned short)(cep.w >> 16));
    } else {
      float4 wa = *(const float4*)((const float*)ewraw + e0);
      float4 wb = *(const float4*)((const float*)ewraw + e0 + 4);
      float4 ca = *(const float4*)((const float*)ceraw + e0);
      float4 cb = *(const float4*)((const float*)ceraw + e0 + 4);
      ew0 = wa.x; ew1 = wa.y; ew2 = wa.z; ew3 = wa.w;
      ew4 = wb.x; ew5 = wb.y; ew6 = wb.z; ew7 = wb.w;
      ce0 = ca.x; ce1 = ca.y; ce2 = ca.z; ce3 = ca.w;
      ce4 = cb.x; ce5 = cb.y; ce6 = cb.z; ce7 = cb.w;
    }
    float o00 = b0 + ew0 * M00 + ce0 * M10 + sv0.x + dv0.x;
    float o10 = b1 + ew0 * M01 + ce0 * M11 + sv0.y + dv0.y;
    float o01 = b0 + ew1 * M00 + ce1 * M10 + sv1.x + dv1.x;
    float o11 = b1 + ew1 * M01 + ce1 * M11 + sv1.y + dv1.y;
    float o02 = b0 + ew2 * M00 + ce2 * M10 + sv2.x + dv2.x;
    float o12 = b1 + ew2 * M01 + ce2 * M11 + sv2.y + dv2.y;
    float o03 = b0 + ew3 * M00 + ce3 * M10 + sv3.x + dv3.x;
    float o13 = b1 + ew3 * M01 + ce3 * M11 + sv3.y + dv3.y;
    float o04 = b0 + ew4 * M00 + ce4 * M10 + sv4.x + dv4.x;
    float o14 = b1 + ew4 * M01 + ce4 * M11 + sv4.y + dv4.y;
    float o05 = b0 + ew5 * M00 + ce5 * M10 + sv5.x + dv5.x;
    float o15 = b1 + ew5 * M01 + ce5 * M11 + sv5.y + dv5.y;
    float o06 = b0 + ew6 * M00 + ce6 * M10 + sv6.x + dv6.x;
    float o16 = b1 + ew6 * M01 + ce6 * M11 + sv6.y + dv6.y;
    float o07 = b0 + ew7 * M00 + ce7 * M10 + sv7.x + dv7.x;
    float o17 = b1 + ew7 * M01 + ce7 * M11 + sv7.y + dv7.y;
    if (bf) {
      uint4 pka, pkb;
      pka.x = ((unsigned int)f2bf(o10) << 16) | (unsigned int)f2bf(o00);
      pka.y = ((unsigned int)f2bf(o11) << 16) | (unsigned int)f2bf(o01);
      pka.z = ((unsigned int)f2bf(o12) << 16) | (unsigned int)f2bf(o02);
      pka.w = ((unsigned int)f2bf(o13) << 16) | (unsigned int)f2bf(o03);
      pkb.x = ((unsigned int)f2bf(o14) << 16) | (unsigned int)f2bf(o04);
      pkb.y = ((unsigned int)f2bf(o15) << 16) | (unsigned int)f2bf(o05);
      pkb.z = ((unsigned int)f2bf(o16) << 16) | (unsigned int)f2bf(o06);
      pkb.w = ((unsigned int)f2bf(o17) << 16) | (unsigned int)f2bf(o07);
      unsigned int* ob = (unsigned int*)out + e0;
      *(uint4*)ob = pka;            // lane-contiguous 32B total
      *(uint4*)(ob + 4) = pkb;
    } else {
      float4 w0, w1, w2, w3;
      w0.x = o00; w0.y = o10; w0.z = o01; w0.w = o11;
      w1.x = o02; w1.y = o12; w1.z = o03; w1.w = o13;
      w2.x = o04; w2.y = o14; w2.z = o05; w2.w = o15;
      w3.x = o06; w3.y = o16; w3.z = o07; w3.w = o17;
      float* ob = (float*)out + (size_t)e0 * 2;
      *(float4*)ob = w0;
      *(float4*)(ob + 4) = w1;
      *(float4*)(ob + 8) = w2;
      *(float4*)(ob + 12) = w3;
    }
  } else {
    for (int e = e0; e < E; e++) {
      float ew = bf ? bf2f(((const unsigned short*)ewraw)[e]) : ((const float*)ewraw)[e];
      float ce = bf ? bf2f(((const unsigned short*)ceraw)[e]) : ((const float*)ceraw)[e];
      float2 sv = ps2[src[e]];
      float2 dv = pd2[dst[e]];
      float o0 = b0 + ew * M00 + ce * M10 + sv.x + dv.x;
      float o1 = b1 + ew * M01 + ce * M11 + sv.y + dv.y;
      if (bf) {
        unsigned int pk = ((unsigned int)f2bf(o1) << 16) | (unsigned int)f2bf(o0);
        ((unsigned int*)out)[e] = pk;
      } else {
        float2 r; r.x = o0; r.y = o1;
        ((float2*)out)[e] = r;
      }
    }
  }
}

extern "C" void kernel_launch(void* const* d_in, const int* in_sizes, int n_in,
                              void* d_out, int out_size, void* d_ws, size_t ws_size,
                              hipStream_t stream) {
  const int* eidx = (const int*)d_in[0];
  const int E = in_sizes[0] / 2;
  const int N = NNODES;
  const int* src = eidx;
  const int* dst = eidx + E;
  int chunk = (E + FBC - 1) / FBC;
  chunk = (chunk + 3) & ~3;                 // multiple of 4 for int4 loads
  if (chunk > STCAP) chunk = (E + FBC - 1) / FBC;  // safety (then scalar path)

  char* ws = (char*)d_ws;
  size_t off = 0;
  size_t off_mode = off; off += 256;
  size_t off_wsm  = off; off += (size_t)WSM_TOTAL * 4;
  off = (off + 255) & ~(size_t)255;
  size_t off_cnts = off; off += (size_t)KB * FBC * 4;
  size_t off_pfx  = off; off += (size_t)KB * FBC * 4;
  size_t off_tot  = off; off += (size_t)KB * 4;
  off = (off + 255) & ~(size_t)255;
  size_t off_base = off; off += (size_t)(KB + 1) * 4;
  off = (off + 255) & ~(size_t)255;
  size_t off_recs = off; off += (size_t)E * 4;
  size_t off_dinv = off; off += (size_t)N * 4;
  off = (off + 255) & ~(size_t)255;
  size_t off_recq = off; off += (size_t)N * 16;
  size_t off_ps2  = off; off += (size_t)N * 8;
  size_t off_pd2  = off; off += (size_t)N * 8;
  off = (off + 255) & ~(size_t)255;
  size_t off_ABg  = off; off += (size_t)KB * ABSTR * 4;
  if (ws_size < off) return;

  int*          mode   = (int*)(ws + off_mode);
  float*        wsm    = (float*)(ws + off_wsm);
  int*          counts = (int*)(ws + off_cnts);
  int*          prefx  = (int*)(ws + off_pfx);
  int*          totals = (int*)(ws + off_tot);
  int*          bases  = (int*)(ws + off_base);
  unsigned int* recs   = (unsigned int*)(ws + off_recs);
  float*        dinv   = (float*)(ws + off_dinv);
  uint4*        recq   = (uint4*)(ws + off_recq);
  float2*       ps2    = (float2*)(ws + off_ps2);
  float2*       pd2    = (float2*)(ws + off_pd2);
  float*        ABg    = (float*)(ws + off_ABg);

  k_setup<<<1, 1024, 0, stream>>>((const unsigned short*)d_in[1],
      d_in[4], d_in[5], d_in[6], d_in[7], d_in[8], d_in[9], d_in[10],
      d_in[11], d_in[12], d_in[13], d_in[14], d_in[15], mode, wsm);
  k_hist<<<FBC, 1024, 0, stream>>>(dst, counts, E, chunk);
  k_scanA<<<KB, FBC, 0, stream>>>(counts, prefx, totals);
  k_scanB<<<1, 1024, 0, stream>>>(totals, bases);
  k_fillsort<<<FBC, 1024, 0, stream>>>(src, dst, counts, prefx, bases, recs, E, chunk);
  k_degdinv<<<KB, 1024, 0, stream>>>(recs, bases, dinv, N);
  k_sA<<<KB, 1024, 0, stream>>>(wsm, recs, bases, dinv, recq, N);
  k_ABacc<<<KB, 1024, 0, stream>>>(recs, bases, recq, ABg, N);
  k_node2<<<(N + 255) / 256, 256, 0, stream>>>(wsm, ABg, recq, ps2, pd2, N);
  {
    long long tot = ((long long)E + UE - 1) / UE;
    int blocks = (int)((tot + 255) / 256);
    k_edge<<<blocks, 256, 0, stream>>>(wsm, src, dst, d_in[1], d_in[2],
                                       ps2, pd2, d_out, mode, E);
  }
}

// Round 17
// 171.697 us; speedup vs baseline: 1.0184x; 1.0184x over previous
//
#include <hip/hip_runtime.h>
#include <hip/hip_bf16.h>

// ---------------------------------------------------------------------------
// KEPCE_GCN, round 17 = exact revert to R15 (best measured: 170.4us).
//  R16's UE=8 k_edge regressed (occupancy 33%, 42.7us vs 40.5us); k_edge is
//  at the random-gather request-rate floor -- UE=4 named-scalar variant is
//  the best point found. All sweep kernels at their DS-atomic-pipe floors.
// ---------------------------------------------------------------------------

#define NNODES 100000
#define NREG   17
#define KB     782          // buckets = ceil(100000/128)
#define FBC    256          // chunk blocks
#define STCAP  12544        // LDS staging capacity (>= chunk)
#define LSTR64 19           // u64 row stride for AB planes (17 + pad)
#define ABSTR  4352         // 34*128 floats per bucket in ABg
#define QSCALE 4194304.0f   // 2^22
#define INVQ   2.384185791015625e-7f

// wsm element offsets (f32)
#define O_W0    0
#define O_B0    8
#define O_W1    16
#define O_B1    144
#define O_W2    160
#define O_B2C   672
#define O_WN    704
#define O_BN    1728
#define O_WE1   1760
#define O_BE1   3872
#define O_WE2   3904
#define O_BE2   3968
#define WSM_N   3970
#define O_H0    3972
#define O_TS    3992
#define O_NT    4008
#define O_U     4016   // 17*32
#define O_WWR   4560   // 17*32
#define O_M     5104   // 66*2
#define O_BIAS2 5236
#define WSM_TOTAL 6144

__device__ __forceinline__ float bf2f(unsigned short u) {
  union { float f; unsigned int i; } v; v.i = ((unsigned int)u) << 16; return v.f;
}
__device__ __forceinline__ unsigned short f2bf(float f) {
  union { float f; unsigned int i; } v; v.f = f;
  unsigned int x = v.i;
  return (unsigned short)((x + 0x7FFFu + ((x >> 16) & 1u)) >> 16);
}
__device__ __forceinline__ float relu_(float x) { return x > 0.f ? x : 0.f; }

// fused: dtype detect + weight convert + derived-tensor prep (one block)
__global__ __launch_bounds__(1024) void k_setup(
    const unsigned short* ewraw,
    const void* p0, const void* p1, const void* p2, const void* p3,
    const void* p4, const void* p5, const void* p6, const void* p7,
    const void* p8, const void* p9, const void* p10, const void* p11,
    int* mode, float* wsm) {
  __shared__ int cnt, smode, snt;
  __shared__ float h0[16], ts[16];
  int t = threadIdx.x;
  if (t == 0) cnt = 0;
  __syncthreads();
  int ok = 0;
  for (int i = t; i < 512; i += blockDim.x) {
    unsigned short h = ewraw[i];
    int e = (h >> 7) & 0xFF;
    if (!(h & 0x8000) && e >= 0x70 && e <= 0x7E) ok++;
  }
  atomicAdd(&cnt, ok);
  __syncthreads();
  if (t == 0) { smode = (cnt >= 400) ? 1 : 0; *mode = smode; }
  __syncthreads();
  int bf = smode;
  const void* ptrs[12] = {p0,p1,p2,p3,p4,p5,p6,p7,p8,p9,p10,p11};
  const int offs[13] = {O_W0,O_B0,O_W1,O_B1,O_W2,O_B2C,O_WN,O_BN,O_WE1,O_BE1,O_WE2,O_BE2,WSM_N};
  for (int idx = t; idx < WSM_N; idx += blockDim.x) {
    int seg = 0;
    while (idx >= offs[seg + 1]) seg++;
    int k = idx - offs[seg];
    wsm[idx] = bf ? bf2f(((const unsigned short*)ptrs[seg])[k])
                  : ((const float*)ptrs[seg])[k];
  }
  __syncthreads();
  if (t < 16) {
    float acc = 0.f;
    for (int j = 0; j < 8; j++)
      acc += (wsm[O_W0 + j] + wsm[O_B0 + j]) * wsm[O_W1 + j * 16 + t];
    h0[t] = acc;
    wsm[O_H0 + t] = acc;
  }
  __syncthreads();
  if (t == 0) {
    int n = 0;
    for (int j = 0; j < 16; j++) {
      float h = h0[j], b = wsm[O_B1 + j];
      if (h != 0.f) {
        float tj = -b / h;
        if (tj > 0.f) {
          int p = n++;
          while (p > 0 && ts[p - 1] > tj) { ts[p] = ts[p - 1]; p--; }
          ts[p] = tj;
        }
      }
    }
    snt = n;
    wsm[O_NT] = (float)n;
    for (int i = 0; i < n; i++) wsm[O_TS + i] = ts[i];
  }
  __syncthreads();
  int n = snt;
  for (int r = 0; r <= n; r++) {
    float srep;
    if (n == 0) srep = 1.f;
    else if (r == 0) srep = ts[0] * 0.5f;
    else if (r == n) srep = ts[n - 1] * 2.f + 1.f;
    else srep = 0.5f * (ts[r - 1] + ts[r]);
    if (t < 32) {
      float uu = 0.f, ww = 0.f;
      for (int j = 0; j < 16; j++) {
        float h = h0[j], b = wsm[O_B1 + j];
        if (srep * h + b > 0.f) {
          float w2 = wsm[O_W2 + j * 32 + t];
          uu += h * w2;
          ww += b * w2;
        }
      }
      wsm[O_U + r * 32 + t] = uu;
      wsm[O_WWR + r * 32 + t] = ww;
    }
  }
  for (int i = t; i < 66; i += blockDim.x) {
    float m0 = 0.f, m1 = 0.f;
    for (int k = 0; k < 32; k++) {
      float w1 = wsm[O_WE1 + i * 32 + k];
      m0 += w1 * wsm[O_WE2 + k * 2 + 0];
      m1 += w1 * wsm[O_WE2 + k * 2 + 1];
    }
    wsm[O_M + i * 2 + 0] = m0;
    wsm[O_M + i * 2 + 1] = m1;
  }
  if (t == 0) {
    float b20 = wsm[O_BE2 + 0], b21 = wsm[O_BE2 + 1];
    for (int k = 0; k < 32; k++) {
      b20 += wsm[O_BE1 + k] * wsm[O_WE2 + k * 2 + 0];
      b21 += wsm[O_BE1 + k] * wsm[O_WE2 + k * 2 + 1];
    }
    wsm[O_BIAS2 + 0] = b20;
    wsm[O_BIAS2 + 1] = b21;
  }
}

// --- bucket radix partition (atomic-free globally) -------------------------
__global__ __launch_bounds__(1024) void k_hist(const int* __restrict__ dst,
                                               int* __restrict__ counts,
                                               int E, int chunk) {
  __shared__ int h[KB];
  for (int i = threadIdx.x; i < KB; i += blockDim.x) h[i] = 0;
  __syncthreads();
  int b = blockIdx.x;
  int start = b * chunk, end = min(E, start + chunk);
  int tid = threadIdx.x, BD = blockDim.x;
  bool va = ((chunk & 3) == 0) && ((((unsigned long long)(const void*)dst) & 15ull) == 0ull);
  if (va) {
    for (int base = start; base < end; base += BD * 4) {
      int idx = base + tid * 4;
      if (idx + 4 <= end) {
        int4 d4 = *(const int4*)(dst + idx);
        atomicAdd(&h[d4.x >> 7], 1);
        atomicAdd(&h[d4.y >> 7], 1);
        atomicAdd(&h[d4.z >> 7], 1);
        atomicAdd(&h[d4.w >> 7], 1);
      } else {
        for (int e = idx; e < end; e++) atomicAdd(&h[dst[e] >> 7], 1);
      }
    }
  } else {
    for (int base = start; base < end; base += BD * 4) {
#pragma unroll
      for (int u = 0; u < 4; u++) {
        int idx = base + u * BD + tid;
        if (idx < end) atomicAdd(&h[dst[idx] >> 7], 1);
      }
    }
  }
  __syncthreads();
  for (int i = threadIdx.x; i < KB; i += blockDim.x)
    counts[i * FBC + b] = h[i];
}

__global__ __launch_bounds__(FBC) void k_scanA(const int* __restrict__ counts,
                                               int* __restrict__ prefx,
                                               int* __restrict__ totals) {
  __shared__ int s[FBC];
  int k = blockIdx.x, t = threadIdx.x;
  int v = counts[k * FBC + t];
  s[t] = v;
  __syncthreads();
  for (int off = 1; off < FBC; off <<= 1) {
    int add = (t >= off) ? s[t - off] : 0;
    __syncthreads();
    s[t] += add;
    __syncthreads();
  }
  prefx[k * FBC + t] = s[t] - v;
  if (t == FBC - 1) totals[k] = s[t];
}

__global__ __launch_bounds__(1024) void k_scanB(const int* __restrict__ totals,
                                                int* __restrict__ bases) {
  __shared__ int s[1024];
  int t = threadIdx.x;
  int v = (t < KB) ? totals[t] : 0;
  s[t] = v;
  __syncthreads();
  for (int off = 1; off < 1024; off <<= 1) {
    int add = (t >= off) ? s[t - off] : 0;
    __syncthreads();
    s[t] += add;
    __syncthreads();
  }
  if (t < KB) bases[t] = s[t] - v;
  if (t == KB - 1) bases[KB] = s[t];
}

__global__ __launch_bounds__(1024) void k_fillsort(const int* __restrict__ src,
                                                   const int* __restrict__ dst,
                                                   const int* __restrict__ counts,
                                                   const int* __restrict__ prefx,
                                                   const int* __restrict__ bases,
                                                   unsigned int* __restrict__ recs,
                                                   int E, int chunk) {
  __shared__ unsigned int staged[STCAP];
  __shared__ int cnt[KB], r0o[KB + 1], r0c[KB], tgt[KB];
  int b = blockIdx.x;
  int tid = threadIdx.x, BD = blockDim.x;
  for (int i = tid; i < KB; i += BD) {
    cnt[i] = counts[i * FBC + b];
    tgt[i] = bases[i] + prefx[i * FBC + b];
  }
  __syncthreads();
  int start = b * chunk, end = min(E, start + chunk);
  int rn = end - start;
  if (tid < KB) r0o[tid] = cnt[tid];
  __syncthreads();
  for (int off = 1; off < KB; off <<= 1) {
    int add = 0;
    if (tid < KB && tid >= off) add = r0o[tid - off];
    __syncthreads();
    if (tid < KB) r0o[tid] += add;
    __syncthreads();
  }
  if (tid < KB) r0c[tid] = r0o[tid] - cnt[tid];
  __syncthreads();
  if (tid < KB) r0o[tid] = r0c[tid];
  if (tid == 0) r0o[KB] = rn;
  __syncthreads();
  bool va = ((chunk & 3) == 0) &&
            ((((unsigned long long)(const void*)dst) & 15ull) == 0ull) &&
            ((((unsigned long long)(const void*)src) & 15ull) == 0ull);
  if (va) {
    for (int base = 0; base < rn; base += BD * 4) {
      int idx = base + tid * 4;
      if (idx + 4 <= rn) {
        int4 d4 = *(const int4*)(dst + start + idx);
        int4 s4 = *(const int4*)(src + start + idx);
        int p0 = atomicAdd(&r0c[d4.x >> 7], 1);
        staged[p0] = ((unsigned int)s4.x << 7) | (unsigned int)(d4.x & 127);
        int p1 = atomicAdd(&r0c[d4.y >> 7], 1);
        staged[p1] = ((unsigned int)s4.y << 7) | (unsigned int)(d4.y & 127);
        int p2 = atomicAdd(&r0c[d4.z >> 7], 1);
        staged[p2] = ((unsigned int)s4.z << 7) | (unsigned int)(d4.z & 127);
        int p3 = atomicAdd(&r0c[d4.w >> 7], 1);
        staged[p3] = ((unsigned int)s4.w << 7) | (unsigned int)(d4.w & 127);
      } else {
        for (int e2 = idx; e2 < rn; e2++) {
          int d = dst[start + e2];
          int s = src[start + e2];
          int pos = atomicAdd(&r0c[d >> 7], 1);
          staged[pos] = ((unsigned int)s << 7) | (unsigned int)(d & 127);
        }
      }
    }
  } else {
    for (int base = 0; base < rn; base += BD * 4) {
#pragma unroll
      for (int u = 0; u < 4; u++) {
        int idx = base + u * BD + tid;
        if (idx < rn) {
          int d = dst[start + idx];
          int s = src[start + idx];
          int pos = atomicAdd(&r0c[d >> 7], 1);
          staged[pos] = ((unsigned int)s << 7) | (unsigned int)(d & 127);
        }
      }
    }
  }
  __syncthreads();
  int nquads = (rn + 3) >> 2;
  for (int q = tid; q < nquads; q += BD) {
    int t0 = q * 4;
    int lo = 0, hi = KB;
    while (hi - lo > 1) {
      int mid = (lo + hi) >> 1;
      if (r0o[mid] <= t0) lo = mid; else hi = mid;
    }
    int tend = min(t0 + 4, rn);
    for (int t = t0; t < tend; t++) {
      while (t >= r0o[lo + 1]) lo++;
      recs[tgt[lo] + (t - r0o[lo])] = staged[t];
    }
  }
}

// --- per-bucket passes -----------------------------------------------------
#define UDG 4
__global__ __launch_bounds__(1024) void k_degdinv(const unsigned int* __restrict__ recs,
                                                  const int* __restrict__ bases,
                                                  float* __restrict__ dinv, int N) {
  __shared__ int cnt[128];
  if (threadIdx.x < 128) cnt[threadIdx.x] = 0;
  __syncthreads();
  int k = blockIdx.x;
  int s0 = bases[k], n = bases[k + 1] - s0;
  const unsigned int* rp = recs + s0;
  int tid = threadIdx.x, BD = blockDim.x;
  for (int base = 0; base < n; base += BD * UDG) {
    unsigned int r[UDG]; int ok[UDG];
#pragma unroll
    for (int u = 0; u < UDG; u++) {
      int idx = base + u * BD + tid;
      ok[u] = idx < n;
      r[u] = ok[u] ? rp[idx] : 0u;
    }
#pragma unroll
    for (int u = 0; u < UDG; u++)
      if (ok[u]) atomicAdd(&cnt[r[u] & 127u], 1);
  }
  __syncthreads();
  if (threadIdx.x < 128) {
    int v = k * 128 + threadIdx.x;
    if (v < N) dinv[v] = rsqrtf((float)cnt[threadIdx.x] + 1.0f);
  }
}

// emits recq = (alphaQ, betaQ, region, dv-bits)
#define USA 4
__global__ __launch_bounds__(1024) void k_sA(const float* __restrict__ wsm,
                                             const unsigned int* __restrict__ recs,
                                             const int* __restrict__ bases,
                                             const float* __restrict__ dinv,
                                             uint4* __restrict__ recq, int N) {
  __shared__ float acc[128];
  __shared__ float ts[16];
  __shared__ int nt;
  if (threadIdx.x < 128) acc[threadIdx.x] = 0.f;
  if (threadIdx.x == 0) nt = (int)wsm[O_NT];
  if (threadIdx.x < 16) ts[threadIdx.x] = wsm[O_TS + threadIdx.x];
  __syncthreads();
  int k = blockIdx.x;
  int s0 = bases[k], n = bases[k + 1] - s0;
  const unsigned int* rp = recs + s0;
  int tid = threadIdx.x, BD = blockDim.x;
  for (int base = 0; base < n; base += BD * USA) {
    unsigned int r[USA]; int ok[USA];
#pragma unroll
    for (int u = 0; u < USA; u++) {
      int idx = base + u * BD + tid;
      ok[u] = idx < n;
      r[u] = ok[u] ? rp[idx] : 0u;
    }
    float dv[USA];
#pragma unroll
    for (int u = 0; u < USA; u++) dv[u] = ok[u] ? dinv[r[u] >> 7] : 0.f;
#pragma unroll
    for (int u = 0; u < USA; u++)
      if (ok[u]) atomicAdd(&acc[r[u] & 127u], dv[u]);
  }
  __syncthreads();
  if (threadIdx.x < 128) {
    int v = k * 128 + threadIdx.x;
    if (v < N) {
      float dv = dinv[v];
      float s = dv * (acc[threadIdx.x] + dv);
      int rr = 0;
      for (int i = 0; i < nt; i++) rr += (ts[i] < s) ? 1 : 0;
      float alpha = dv * s;
      uint4 q;
      q.x = (unsigned int)(alpha * QSCALE + 0.5f);
      q.y = (unsigned int)(dv * QSCALE + 0.5f);
      q.z = (unsigned int)rr;
      q.w = __float_as_uint(dv);
      recq[v] = q;
    }
  }
}

// one packed u64 LDS atomic per edge; decode to ABg planes
#define UAB 4
__global__ __launch_bounds__(1024) void k_ABacc(const unsigned int* __restrict__ recs,
                                                const int* __restrict__ bases,
                                                const uint4* __restrict__ recq,
                                                float* __restrict__ ABg, int N) {
  __shared__ unsigned long long Lu[128 * LSTR64];
  for (int i = threadIdx.x; i < 128 * LSTR64; i += blockDim.x) Lu[i] = 0ull;
  __syncthreads();
  int k = blockIdx.x;
  int s0 = bases[k], n = bases[k + 1] - s0;
  const unsigned int* rp = recs + s0;
  int tid = threadIdx.x, BD = blockDim.x;
  for (int base = 0; base < n; base += BD * UAB) {
    unsigned int r[UAB]; int ok[UAB];
#pragma unroll
    for (int u = 0; u < UAB; u++) {
      int idx = base + u * BD + tid;
      ok[u] = idx < n;
      r[u] = ok[u] ? rp[idx] : 0u;
    }
    uint4 q[UAB];
#pragma unroll
    for (int u = 0; u < UAB; u++) {
      q[u] = make_uint4(0u, 0u, 0u, 0u);
      if (ok[u]) q[u] = recq[r[u] >> 7];
    }
#pragma unroll
    for (int u = 0; u < UAB; u++) {
      if (ok[u]) {
        unsigned long long c = ((unsigned long long)q[u].x << 32) | (unsigned long long)q[u].y;
        atomicAdd(&Lu[(int)(r[u] & 127u) * LSTR64 + (int)q[u].z], c);
      }
    }
  }
  __syncthreads();
  float* out = ABg + (size_t)k * ABSTR;
  for (int i = tid; i < 34 * 128; i += BD) {
    int r = i >> 7, v = i & 127;
    unsigned long long w;
    float val;
    if (r < NREG) {
      w = Lu[v * LSTR64 + r];
      val = (float)((unsigned int)(w >> 32)) * INVQ;
    } else {
      w = Lu[v * LSTR64 + (r - NREG)];
      val = (float)((unsigned int)(w & 0xFFFFFFFFull)) * INVQ;
    }
    out[i] = val;
  }
}

// per node: AB planes -> x2 -> x3 -> (ps, pd) split tables
__global__ __launch_bounds__(256) void k_node2(const float* __restrict__ wsm,
                                               const float* __restrict__ ABg,
                                               const uint4* __restrict__ recq,
                                               float2* __restrict__ ps2,
                                               float2* __restrict__ pd2, int N) {
  __shared__ float sU[NREG * 32], sW[NREG * 32], sB2[32], sWn[1024], sBn[32], sM[132];
  for (int i = threadIdx.x; i < NREG * 32; i += blockDim.x) {
    sU[i] = wsm[O_U + i];
    sW[i] = wsm[O_WWR + i];
  }
  for (int i = threadIdx.x; i < 1024; i += blockDim.x) sWn[i] = wsm[O_WN + i];
  if (threadIdx.x < 32) {
    sB2[threadIdx.x] = wsm[O_B2C + threadIdx.x];
    sBn[threadIdx.x] = wsm[O_BN + threadIdx.x];
  }
  for (int i = threadIdx.x; i < 132; i += blockDim.x) sM[i] = wsm[O_M + i];
  __syncthreads();
  int v = blockIdx.x * blockDim.x + threadIdx.x;
  if (v >= N) return;
  uint4 self = recq[v];
  float dv = __uint_as_float(self.w);
  float selfa = (float)self.x * INVQ;
  int sr = (int)self.z;
  const float* pb = ABg + (size_t)(v >> 7) * ABSTR + (v & 127);
  float A[NREG], B[NREG];
#pragma unroll
  for (int r = 0; r < NREG; r++) {
    A[r] = pb[r * 128];
    B[r] = pb[(NREG + r) * 128];
  }
  float acc[32];
#pragma unroll
  for (int j = 0; j < 32; j++) acc[j] = 0.f;
#pragma unroll
  for (int r = 0; r < NREG; r++) {
    float Ar = A[r] + ((r == sr) ? selfa : 0.f);
    float Br = B[r] + ((r == sr) ? dv : 0.f);
    if (Ar != 0.f || Br != 0.f) {
#pragma unroll
      for (int j = 0; j < 32; j++)
        acc[j] += Ar * sU[r * 32 + j] + Br * sW[r * 32 + j];
    }
  }
#pragma unroll
  for (int j = 0; j < 32; j++) acc[j] = relu_(dv * acc[j] + sB2[j]);  // x2
  float x3[32];
#pragma unroll
  for (int j = 0; j < 32; j++) {
    float a = sBn[j];
#pragma unroll
    for (int q2 = 0; q2 < 32; q2++) a += acc[q2] * sWn[q2 * 32 + j];
    x3[j] = relu_(a);
  }
  float ps0 = 0.f, ps1 = 0.f, pd0 = 0.f, pd1 = 0.f;
#pragma unroll
  for (int j = 0; j < 32; j++) {
    float x = x3[j];
    ps0 += x * sM[(2 + j) * 2 + 0];
    ps1 += x * sM[(2 + j) * 2 + 1];
    pd0 += x * sM[(34 + j) * 2 + 0];
    pd1 += x * sM[(34 + j) * 2 + 1];
  }
  ps2[v] = make_float2(ps0, ps1);
  pd2[v] = make_float2(pd0, pd1);
}

#define UE 4
__global__ __launch_bounds__(256, 4) void k_edge(const float* __restrict__ wsm,
                                                 const int* __restrict__ src,
                                                 const int* __restrict__ dst,
                                                 const void* __restrict__ ewraw,
                                                 const void* __restrict__ ceraw,
                                                 const float2* __restrict__ ps2,
                                                 const float2* __restrict__ pd2,
                                                 void* __restrict__ out,
                                                 const int* __restrict__ mode, int E) {
  int e0 = (blockIdx.x * blockDim.x + threadIdx.x) * UE;
  bool bf = (*mode) != 0;
  float b0 = wsm[O_BIAS2 + 0], b1 = wsm[O_BIAS2 + 1];
  float M00 = wsm[O_M + 0], M01 = wsm[O_M + 1];
  float M10 = wsm[O_M + 2], M11 = wsm[O_M + 3];
  if (e0 + UE <= E) {
    int4 s4i = *(const int4*)(src + e0);
    int4 d4i = *(const int4*)(dst + e0);
    // all gathers issued through named scalars (SROA-friendly; no &local)
    float2 sv0 = ps2[s4i.x];
    float2 sv1 = ps2[s4i.y];
    float2 sv2 = ps2[s4i.z];
    float2 sv3 = ps2[s4i.w];
    float2 dv0 = pd2[d4i.x];
    float2 dv1 = pd2[d4i.y];
    float2 dv2 = pd2[d4i.z];
    float2 dv3 = pd2[d4i.w];
    float ew0, ew1, ew2, ew3, ce0, ce1, ce2, ce3;
    if (bf) {
      uint2 ewp = *(const uint2*)((const unsigned short*)ewraw + e0);
      uint2 cep = *(const uint2*)((const unsigned short*)ceraw + e0);
      ew0 = bf2f((unsigned short)(ewp.x & 0xFFFFu));
      ew1 = bf2f((unsigned short)(ewp.x >> 16));
      ew2 = bf2f((unsigned short)(ewp.y & 0xFFFFu));
      ew3 = bf2f((unsigned short)(ewp.y >> 16));
      ce0 = bf2f((unsigned short)(cep.x & 0xFFFFu));
      ce1 = bf2f((unsigned short)(cep.x >> 16));
      ce2 = bf2f((unsigned short)(cep.y & 0xFFFFu));
      ce3 = bf2f((unsigned short)(cep.y >> 16));
    } else {
      float4 w = *(const float4*)((const float*)ewraw + e0);
      float4 c = *(const float4*)((const float*)ceraw + e0);
      ew0 = w.x; ew1 = w.y; ew2 = w.z; ew3 = w.w;
      ce0 = c.x; ce1 = c.y; ce2 = c.z; ce3 = c.w;
    }
    float o00 = b0 + ew0 * M00 + ce0 * M10 + sv0.x + dv0.x;
    float o10 = b1 + ew0 * M01 + ce0 * M11 + sv0.y + dv0.y;
    float o01 = b0 + ew1 * M00 + ce1 * M10 + sv1.x + dv1.x;
    float o11 = b1 + ew1 * M01 + ce1 * M11 + sv1.y + dv1.y;
    float o02 = b0 + ew2 * M00 + ce2 * M10 + sv2.x + dv2.x;
    float o12 = b1 + ew2 * M01 + ce2 * M11 + sv2.y + dv2.y;
    float o03 = b0 + ew3 * M00 + ce3 * M10 + sv3.x + dv3.x;
    float o13 = b1 + ew3 * M01 + ce3 * M11 + sv3.y + dv3.y;
    if (bf) {
      uint4 pk;
      pk.x = ((unsigned int)f2bf(o10) << 16) | (unsigned int)f2bf(o00);
      pk.y = ((unsigned int)f2bf(o11) << 16) | (unsigned int)f2bf(o01);
      pk.z = ((unsigned int)f2bf(o12) << 16) | (unsigned int)f2bf(o02);
      pk.w = ((unsigned int)f2bf(o13) << 16) | (unsigned int)f2bf(o03);
      *(uint4*)((unsigned int*)out + e0) = pk;      // 16B/lane contiguous
    } else {
      float4 w0, w1;
      w0.x = o00; w0.y = o10; w0.z = o01; w0.w = o11;
      w1.x = o02; w1.y = o12; w1.z = o03; w1.w = o13;
      float* ob = (float*)out + (size_t)e0 * 2;
      *(float4*)ob = w0;
      *(float4*)(ob + 4) = w1;
    }
  } else {
    for (int e = e0; e < E; e++) {
      float ew = bf ? bf2f(((const unsigned short*)ewraw)[e]) : ((const float*)ewraw)[e];
      float ce = bf ? bf2f(((const unsigned short*)ceraw)[e]) : ((const float*)ceraw)[e];
      float2 sv = ps2[src[e]];
      float2 dv = pd2[dst[e]];
      float o0 = b0 + ew * M00 + ce * M10 + sv.x + dv.x;
      float o1 = b1 + ew * M01 + ce * M11 + sv.y + dv.y;
      if (bf) {
        unsigned int pk = ((unsigned int)f2bf(o1) << 16) | (unsigned int)f2bf(o0);
        ((unsigned int*)out)[e] = pk;
      } else {
        float2 r; r.x = o0; r.y = o1;
        ((float2*)out)[e] = r;
      }
    }
  }
}

extern "C" void kernel_launch(void* const* d_in, const int* in_sizes, int n_in,
                              void* d_out, int out_size, void* d_ws, size_t ws_size,
                              hipStream_t stream) {
  const int* eidx = (const int*)d_in[0];
  const int E = in_sizes[0] / 2;
  const int N = NNODES;
  const int* src = eidx;
  const int* dst = eidx + E;
  int chunk = (E + FBC - 1) / FBC;
  chunk = (chunk + 3) & ~3;                 // multiple of 4 for int4 loads
  if (chunk > STCAP) chunk = (E + FBC - 1) / FBC;  // safety (then scalar path)

  char* ws = (char*)d_ws;
  size_t off = 0;
  size_t off_mode = off; off += 256;
  size_t off_wsm  = off; off += (size_t)WSM_TOTAL * 4;
  off = (off + 255) & ~(size_t)255;
  size_t off_cnts = off; off += (size_t)KB * FBC * 4;
  size_t off_pfx  = off; off += (size_t)KB * FBC * 4;
  size_t off_tot  = off; off += (size_t)KB * 4;
  off = (off + 255) & ~(size_t)255;
  size_t off_base = off; off += (size_t)(KB + 1) * 4;
  off = (off + 255) & ~(size_t)255;
  size_t off_recs = off; off += (size_t)E * 4;
  size_t off_dinv = off; off += (size_t)N * 4;
  off = (off + 255) & ~(size_t)255;
  size_t off_recq = off; off += (size_t)N * 16;
  size_t off_ps2  = off; off += (size_t)N * 8;
  size_t off_pd2  = off; off += (size_t)N * 8;
  off = (off + 255) & ~(size_t)255;
  size_t off_ABg  = off; off += (size_t)KB * ABSTR * 4;
  if (ws_size < off) return;

  int*          mode   = (int*)(ws + off_mode);
  float*        wsm    = (float*)(ws + off_wsm);
  int*          counts = (int*)(ws + off_cnts);
  int*          prefx  = (int*)(ws + off_pfx);
  int*          totals = (int*)(ws + off_tot);
  int*          bases  = (int*)(ws + off_base);
  unsigned int* recs   = (unsigned int*)(ws + off_recs);
  float*        dinv   = (float*)(ws + off_dinv);
  uint4*        recq   = (uint4*)(ws + off_recq);
  float2*       ps2    = (float2*)(ws + off_ps2);
  float2*       pd2    = (float2*)(ws + off_pd2);
  float*        ABg    = (float*)(ws + off_ABg);

  k_setup<<<1, 1024, 0, stream>>>((const unsigned short*)d_in[1],
      d_in[4], d_in[5], d_in[6], d_in[7], d_in[8], d_in[9], d_in[10],
      d_in[11], d_in[12], d_in[13], d_in[14], d_in[15], mode, wsm);
  k_hist<<<FBC, 1024, 0, stream>>>(dst, counts, E, chunk);
  k_scanA<<<KB, FBC, 0, stream>>>(counts, prefx, totals);
  k_scanB<<<1, 1024, 0, stream>>>(totals, bases);
  k_fillsort<<<FBC, 1024, 0, stream>>>(src, dst, counts, prefx, bases, recs, E, chunk);
  k_degdinv<<<KB, 1024, 0, stream>>>(recs, bases, dinv, N);
  k_sA<<<KB, 1024, 0, stream>>>(wsm, recs, bases, dinv, recq, N);
  k_ABacc<<<KB, 1024, 0, stream>>>(recs, bases, recq, ABg, N);
  k_node2<<<(N + 255) / 256, 256, 0, stream>>>(wsm, ABg, recq, ps2, pd2, N);
  {
    long long tot = ((long long)E + UE - 1) / UE;
    int blocks = (int)((tot + 255) / 256);
    k_edge<<<blocks, 256, 0, stream>>>(wsm, src, dst, d_in[1], d_in[2],
                                       ps2, pd2, d_out, mode, E);
  }
}